// Round 8
// baseline (59.780 us; speedup 1.0000x reference)
//
#include <hip/hip_runtime.h>
#include <hip/hip_bf16.h>

#define Bdim 4096
#define Ldim 4096
#define Hdim 1024
#define BM 256
#define BN 256
#define BK 64
#define NT (Hdim / BK)   // 16 K-tiles

typedef __attribute__((ext_vector_type(8))) __bf16 bf16x8;
typedef __attribute__((ext_vector_type(4))) float floatx4;
typedef __attribute__((ext_vector_type(4))) unsigned short ushortx4;

__device__ __forceinline__ unsigned short f2bf(float f) {
  union { __hip_bfloat16 h; unsigned short u; } c;
  c.h = __float2bfloat16(f);
  return c.u;
}

// ---- fused prep: blocks [0,Ldim) do W->bf16 + bias row; [Ldim,+Bdim) X->bf16
// R7: nontemporal loads on the stream-once fp32 inputs (X,E,W never re-read
// as fp32). R8 fix: __builtin_nontemporal_load requires clang ext-vector
// types, not HIP's float4 class -> use floatx4.
__global__ __launch_bounds__(256) void prep_kernel(
    const float* __restrict__ X, const float* __restrict__ E,
    const float* __restrict__ W, const float* __restrict__ b,
    unsigned short* __restrict__ Xb, unsigned short* __restrict__ Wb,
    float* __restrict__ bias) {
  const int blk = blockIdx.x;
  const int t = threadIdx.x;
  if (blk < Ldim) {
    const int row = blk;
    const floatx4 wv = __builtin_nontemporal_load(
        reinterpret_cast<const floatx4*>(W + (size_t)row * Hdim) + t);
    const floatx4 ev = __builtin_nontemporal_load(
        reinterpret_cast<const floatx4*>(E + (size_t)row * Hdim) + t);
    ushortx4 o;
    o.x = f2bf(wv.x); o.y = f2bf(wv.y); o.z = f2bf(wv.z); o.w = f2bf(wv.w);
    reinterpret_cast<ushortx4*>(Wb + (size_t)row * Hdim)[t] = o;
    float dot = wv.x * ev.x + wv.y * ev.y + wv.z * ev.z + wv.w * ev.w;
#pragma unroll
    for (int off = 32; off > 0; off >>= 1) dot += __shfl_down(dot, off, 64);
    __shared__ float part[4];
    if ((t & 63) == 0) part[t >> 6] = dot;
    __syncthreads();
    if (t == 0) bias[row] = part[0] + part[1] + part[2] + part[3] + b[row];
  } else {
    const int i = (blk - Ldim) * 256 + t;
    floatx4 v = __builtin_nontemporal_load(
        reinterpret_cast<const floatx4*>(X) + i);
    ushortx4 o;
    o.x = f2bf(v.x); o.y = f2bf(v.y); o.z = f2bf(v.z); o.w = f2bf(v.w);
    reinterpret_cast<ushortx4*>(Xb)[i] = o;
  }
}

// ---- C[B,L] = Xb @ Wb^T + bias -----------------------------------------
// R7 = R5 (champion by bench total, 50.2us) with three separable changes:
//  (1) MINIMAL BARRIERS: 6 -> 2 per tile. WAR-hazard audit:
//      - A(t+2) stages into c.A at P2/P3: needs all waves' af reads of c
//        (P0:af0-3, P1:af4-7) complete. Each wave's LGKM0 precedes P1's
//        post-MFMA BAR in program order -> that BAR certifies it. KEEP.
//      - B(t+1) stages into o.B at P0/P1: o.B last read at t-1's P2;
//        every wave's bfv reads retired before t-1's P3 gate-BAR (LGKM0
//        precedes it) -> gate-BAR certifies. KEEP gate.
//      - Pre-MFMA barriers order nothing: intra-wave ds_read->MFMA is a
//        visible data dep (plain C++ loads; compiler emits counted
//        lgkmcnt), and in-flight MFMAs hold operands in REGS, not LDS.
//        REMOVED (P0/P2 pre, P0/P2 post).
//  (2) XCD chunk (bijective, 256 = 8 x 32): xcd = bid&7 owns M-rows
//      {2*xcd, 2*xcd+1} x all 16 N-cols -> A-panels (2 x 0.5MB bf16) stay
//      in the XCD's L2; B streams from LLC once. Predict FETCH 37->~24MB.
//  (3) Nontemporal C stores (write-once, never re-read) -> don't evict
//      A/B panels mid-loop.
// Schedule stream, gate accounting, swizzle: byte-identical to R5:
//   tile t (c=t&1, o=c^1): P0: Bh0(t+1)->o  P1: Bh1(t+1)->o
//                          P2: Ah0(t+2)->c  P3: Ah1(t+2)->c
//   gate at P3: vmcnt(4)+BAR (12 outstanding -> retires all of t+1, keeps
//   A(t+2) in flight); tile 14: stages B(15), GATE0; tile 15: no stage.
// LDS swizzle (T2, conflicts=0 measured): 16B-slot ks of row r at ks^(r&7);
// GLL dest linear, global SOURCE pre-swizzled, reads same XOR.
__global__ __launch_bounds__(512, 2) void gemm_bias_kernel(
    const unsigned short* __restrict__ A,   // [Bdim][Hdim] bf16 bits
    const unsigned short* __restrict__ Bw,  // [Ldim][Hdim] bf16 bits
    const float* __restrict__ bias,         // [Ldim]
    float* __restrict__ C) {                // [Bdim][Ldim] fp32
  __shared__ __align__(16) unsigned short lds[2][2][BM * BK];  // 128 KB

  const int tid = threadIdx.x;
  const int wave = tid >> 6;
  const int lane = tid & 63;
  const int wm = wave >> 2;   // 0..1  (M half)
  const int wn = wave & 3;    // 0..3  (N quarter)

  // XCD-chunked bijective remap (256 wgs = 8 XCDs x 32; 32 = 2M x 16N)
  const int bid = blockIdx.x;
  const int xcd = bid & 7;
  const int idx = bid >> 3;                 // 0..31
  const int m_blk = (xcd * 2 + (idx >> 4)) * BM;
  const int n_blk = (idx & 15) * BN;

  // staging source (pre-swizzled): wave covers rows [wave*8,+8) per GLL
  const int srow = wave * 8 + (lane >> 3);
  const int skofs = ((lane & 7) ^ (lane >> 3)) * 8;
  const unsigned short* gA = A + (size_t)(m_blk + srow) * Hdim + skofs;
  const unsigned short* gB = Bw + (size_t)(n_blk + srow) * Hdim + skofs;

  // fragment read offsets (swizzled): row = base+fr, k 16B-slot = ksl*4+fq
  const int fr = lane & 15;
  const int fq = lane >> 4;
  const int kx0 = ((fq) ^ (fr & 7)) * 8;        // k 0..31
  const int kx1 = ((4 + fq) ^ (fr & 7)) * 8;    // k 32..63
  const int aBase = (wm * 128 + fr) * BK;
  const int bBase = (wn * 64 + fr) * BK;

  floatx4 acc[8][4] = {};
  bf16x8 af[8][2], bfv[4][2];

#define GLL(src, dst)                                                  \
  __builtin_amdgcn_global_load_lds(                                    \
      (const __attribute__((address_space(1))) void*)(src),            \
      (__attribute__((address_space(3))) void*)(dst), 16, 0, 0)

  // stage one half-tile (mat 0=A 1=B, h = row-half) of K-tile kt into buf c
#define STAGE_H(c, mat, h, kt)                                         \
  do {                                                                 \
    const unsigned short* _g = (mat) ? gB : gA;                        \
    GLL(_g + (size_t)((h) * 128) * Hdim + (size_t)(kt) * BK,           \
        &lds[c][mat][((h) * 128 + wave * 8) * BK]);                    \
    GLL(_g + (size_t)((h) * 128 + 64) * Hdim + (size_t)(kt) * BK,      \
        &lds[c][mat][((h) * 128 + 64 + wave * 8) * BK]);               \
  } while (0)

#define READ_A(c, lo)                                                  \
  do {                                                                 \
    _Pragma("unroll") for (int mi = (lo); mi < (lo) + 4; ++mi) {       \
      af[mi][0] = *(const bf16x8*)&lds[c][0][aBase + mi * 16 * BK + kx0]; \
      af[mi][1] = *(const bf16x8*)&lds[c][0][aBase + mi * 16 * BK + kx1]; \
    }                                                                  \
  } while (0)

#define READ_B(c, lo)                                                  \
  do {                                                                 \
    _Pragma("unroll") for (int ni = (lo); ni < (lo) + 2; ++ni) {       \
      bfv[ni][0] = *(const bf16x8*)&lds[c][1][bBase + ni * 16 * BK + kx0]; \
      bfv[ni][1] = *(const bf16x8*)&lds[c][1][bBase + ni * 16 * BK + kx1]; \
    }                                                                  \
  } while (0)

#define MFMA_Q(M0, N0)                                                 \
  do {                                                                 \
    __builtin_amdgcn_s_setprio(1);                                     \
    _Pragma("unroll") for (int mi = (M0); mi < (M0) + 4; ++mi)         \
      _Pragma("unroll") for (int ni = (N0); ni < (N0) + 2; ++ni) {     \
        acc[mi][ni] = __builtin_amdgcn_mfma_f32_16x16x32_bf16(         \
            af[mi][0], bfv[ni][0], acc[mi][ni], 0, 0, 0);              \
        acc[mi][ni] = __builtin_amdgcn_mfma_f32_16x16x32_bf16(         \
            af[mi][1], bfv[ni][1], acc[mi][ni], 0, 0, 0);              \
      }                                                                \
    __builtin_amdgcn_s_setprio(0);                                     \
  } while (0)

#define BAR __builtin_amdgcn_s_barrier()
#define LGKM0 asm volatile("s_waitcnt lgkmcnt(0)" ::: "memory")
#define GATE4 asm volatile("s_waitcnt vmcnt(4)\n\ts_barrier" ::: "memory")
#define GATE0 asm volatile("s_waitcnt vmcnt(0)\n\ts_barrier" ::: "memory")

  // DO_B: stage B(kt+1)->o at P0/P1.  DO_A: stage A(kt+2)->c at P2/P3.
#define TILE_BODY(c, o, kt, DO_B, DO_A, GATE)                          \
  do {                                                                 \
    /* P0 */                                                           \
    if (DO_B) STAGE_H(o, 1, 0, (kt) + 1);                              \
    READ_A(c, 0);                                                      \
    READ_B(c, 0);                                                      \
    LGKM0;                                                             \
    MFMA_Q(0, 0);                                                      \
    /* P1 */                                                           \
    if (DO_B) STAGE_H(o, 1, 1, (kt) + 1);                              \
    READ_A(c, 4);                                                      \
    LGKM0;                                                             \
    MFMA_Q(4, 0);                                                      \
    BAR;  /* load-bearing: all waves' af reads of c done -> c.A free */\
    /* P2 */                                                           \
    if (DO_A) STAGE_H(c, 0, 0, (kt) + 2);                              \
    READ_B(c, 2);                                                      \
    LGKM0;                                                             \
    MFMA_Q(0, 2);                                                      \
    /* P3 */                                                           \
    if (DO_A) STAGE_H(c, 0, 1, (kt) + 2);                              \
    GATE;  /* load-bearing: per-tile rendezvous + vmcnt retire */      \
    MFMA_Q(4, 2);                                                      \
  } while (0)

  // prologue: tile 0 fully + tile 1 A halves (12 GLLs), gate to 4
  STAGE_H(0, 0, 0, 0);
  STAGE_H(0, 0, 1, 0);
  STAGE_H(0, 1, 0, 0);
  STAGE_H(0, 1, 1, 0);
  STAGE_H(1, 0, 0, 1);
  STAGE_H(1, 0, 1, 1);
  GATE4;

#pragma unroll 1
  for (int t = 0; t < NT - 2; t += 2) {
    TILE_BODY(0, 1, t, 1, 1, GATE4);
    TILE_BODY(1, 0, t + 1, 1, 1, GATE4);
  }
  // tile NT-2 (buf 0): stages B(NT-1)->buf1; no A stage; GATE0 drains
  // A(15)+B(15) (B(15) issued 2 phases earlier).
  TILE_BODY(0, 1, NT - 2, 1, 0, GATE0);
  // tile NT-1 (buf 1): all data resident & retired; no stages, no gate.
  TILE_BODY(1, 0, NT - 1, 0, 0, (void)0);

#undef GLL
#undef STAGE_H
#undef READ_A
#undef READ_B
#undef MFMA_Q
#undef BAR
#undef LGKM0
#undef GATE4
#undef GATE0
#undef TILE_BODY

  // epilogue: C/D layout col=lane&15, row=(lane>>4)*4+reg  [m89-verified]
  // nontemporal: C is write-once, never re-read by anyone.
  const int col0 = n_blk + wn * 64 + fr;
  const int row0 = m_blk + wm * 128 + fq * 4;
#pragma unroll
  for (int ni = 0; ni < 4; ++ni) {
    const float bs = bias[col0 + ni * 16];
#pragma unroll
    for (int mi = 0; mi < 8; ++mi) {
      float* cp = C + (size_t)(row0 + mi * 16) * Ldim + (col0 + ni * 16);
      floatx4 v = acc[mi][ni];
      __builtin_nontemporal_store(v.x + bs, cp + 0 * (size_t)Ldim);
      __builtin_nontemporal_store(v.y + bs, cp + 1 * (size_t)Ldim);
      __builtin_nontemporal_store(v.z + bs, cp + 2 * (size_t)Ldim);
      __builtin_nontemporal_store(v.w + bs, cp + 3 * (size_t)Ldim);
    }
  }
}

extern "C" void kernel_launch(void* const* d_in, const int* in_sizes, int n_in,
                              void* d_out, int out_size, void* d_ws, size_t ws_size,
                              hipStream_t stream) {
  const float* X = (const float*)d_in[0];  // bert_output [B,H]
  const float* E = (const float*)d_in[1];  // label_embed [L,H]
  const float* W = (const float*)d_in[2];  // W [L,H]
  const float* b = (const float*)d_in[3];  // b [L]
  // d_in[4] = labels, unused by the reference output.
  float* out = (float*)d_out;

  unsigned short* Xb = (unsigned short*)d_ws;                 // 8 MB
  unsigned short* Wb = Xb + (size_t)Bdim * Hdim;              // 8 MB
  float* bias = (float*)(Wb + (size_t)Ldim * Hdim);           // 16 KB

  prep_kernel<<<Ldim + Bdim, 256, 0, stream>>>(X, E, W, b, Xb, Wb, bias);
  gemm_bias_kernel<<<(Bdim / BM) * (Ldim / BN), 512, 0, stream>>>(Xb, Wb, bias, out);
}

// Round 10
// 49.620 us; speedup vs baseline: 1.2047x; 1.2047x over previous
//
#include <hip/hip_runtime.h>
#include <hip/hip_bf16.h>

#define Bdim 4096
#define Ldim 4096
#define Hdim 1024
#define BM 256
#define BN 256
#define BK 64
#define NT (Hdim / BK)   // 16 K-tiles

typedef __attribute__((ext_vector_type(8))) __bf16 bf16x8;
typedef __attribute__((ext_vector_type(4))) float floatx4;

__device__ __forceinline__ unsigned short f2bf(float f) {
  union { __hip_bfloat16 h; unsigned short u; } c;
  c.h = __float2bfloat16(f);
  return c.u;
}

// ---- prep, R9 rework: 2048 blocks x 256 thr, NO block-wide reductions.
// blocks [0,1024): W->bf16 + bias, 4 rows/block, ONE WAVE PER ROW (pure
//   shfl reduce -- no LDS, no __syncthreads; old version paid a block-wide
//   reduction + barrier for every single 1024-elem row).
// blocks [1024,2048): X->bf16, 4 float4/thread.
// Plain (temporal) loads: R8's nontemporal experiment regressed.
__global__ __launch_bounds__(256) void prep_kernel(
    const float* __restrict__ X, const float* __restrict__ E,
    const float* __restrict__ W, const float* __restrict__ b,
    unsigned short* __restrict__ Xb, unsigned short* __restrict__ Wb,
    float* __restrict__ bias) {
  const int blk = blockIdx.x;
  const int t = threadIdx.x;
  if (blk < 1024) {
    const int wave = t >> 6;
    const int lane = t & 63;
    const int row = blk * 4 + wave;
    const float4* wrow = reinterpret_cast<const float4*>(W + (size_t)row * Hdim);
    const float4* erow = reinterpret_cast<const float4*>(E + (size_t)row * Hdim);
    ushort4* wbrow = reinterpret_cast<ushort4*>(Wb + (size_t)row * Hdim);
    float dot = 0.f;
#pragma unroll
    for (int j = 0; j < 4; ++j) {
      const int idx = lane + j * 64;          // 256 float4 per row
      const float4 wv = wrow[idx];
      const float4 ev = erow[idx];
      ushort4 o;
      o.x = f2bf(wv.x); o.y = f2bf(wv.y); o.z = f2bf(wv.z); o.w = f2bf(wv.w);
      wbrow[idx] = o;
      dot += wv.x * ev.x + wv.y * ev.y + wv.z * ev.z + wv.w * ev.w;
    }
#pragma unroll
    for (int off = 32; off > 0; off >>= 1) dot += __shfl_down(dot, off, 64);
    if (lane == 0) bias[row] = dot + b[row];
  } else {
    const int base = (blk - 1024) * 1024 + t;  // float4 index
    const float4* xs = reinterpret_cast<const float4*>(X);
    ushort4* xd = reinterpret_cast<ushort4*>(Xb);
#pragma unroll
    for (int j = 0; j < 4; ++j) {
      const float4 v = xs[base + j * 256];
      ushort4 o;
      o.x = f2bf(v.x); o.y = f2bf(v.y); o.z = f2bf(v.z); o.w = f2bf(v.w);
      xd[base + j * 256] = o;
    }
  }
}

// ---- C[B,L] = Xb @ Wb^T + bias -----------------------------------------
// R9 gemm = R5 byte-exact (champion, 50.2us total). R8's bundle (barrier
// removal + XCD remap + nontemporal) regressed to 59.8 -> fully reverted.
// 256x256, BK=64, 8 waves (2M x 4N, 128x64 each), 4-phase/tile cadence:
//   P0: [stage Bh0(t+1)->o] reads A(0-3)+B(0-1); BAR; lgkm0; 16 MFMA
//   P1: [stage Bh1(t+1)->o] reads A(4-7);        BAR; lgkm0; 16 MFMA; BAR
//   P2: [stage Ah0(t+2)->c] reads B(2-3);        BAR; lgkm0; 16 MFMA; BAR
//   P3: [stage Ah1(t+2)->c] GATE vmcnt(4)+BAR;               16 MFMA
// WAR: all af reads of c complete at P1's post-MFMA BAR -> A(t+2) into c.A
// at P2/P3 safe; o.B last read at t-1's P2, certified by t-1 P3's gate.
// Gate: at P3 outstanding = A(t+1)[4]+B(t+1)[4]+A(t+2)[4]=12; vmcnt(4)
// retires all of t+1, keeps A(t+2) in flight. Tile 14 stages B(15), GATE0.
// Tile 15: no stage/gate. Never vmcnt(0) mid-loop.
// LDS swizzle (T2, conflicts=0 measured): 16B-slot ks of row r at ks^(r&7);
// GLL dest linear, global SOURCE pre-swizzled, reads same XOR.
__global__ __launch_bounds__(512, 2) void gemm_bias_kernel(
    const unsigned short* __restrict__ A,   // [Bdim][Hdim] bf16 bits
    const unsigned short* __restrict__ Bw,  // [Ldim][Hdim] bf16 bits
    const float* __restrict__ bias,         // [Ldim]
    float* __restrict__ C) {                // [Bdim][Ldim] fp32
  __shared__ __align__(16) unsigned short lds[2][2][BM * BK];  // 128 KB

  const int tid = threadIdx.x;
  const int wave = tid >> 6;
  const int lane = tid & 63;
  const int wm = wave >> 2;   // 0..1  (M half)
  const int wn = wave & 3;    // 0..3  (N quarter)
  const int m_blk = blockIdx.y * BM;
  const int n_blk = blockIdx.x * BN;

  // staging source (pre-swizzled): wave covers rows [wave*8,+8) per GLL
  const int srow = wave * 8 + (lane >> 3);
  const int skofs = ((lane & 7) ^ (lane >> 3)) * 8;
  const unsigned short* gA = A + (size_t)(m_blk + srow) * Hdim + skofs;
  const unsigned short* gB = Bw + (size_t)(n_blk + srow) * Hdim + skofs;

  // fragment read offsets (swizzled): row = base+fr, k 16B-slot = ksl*4+fq
  const int fr = lane & 15;
  const int fq = lane >> 4;
  const int kx0 = ((fq) ^ (fr & 7)) * 8;        // k 0..31
  const int kx1 = ((4 + fq) ^ (fr & 7)) * 8;    // k 32..63
  const int aBase = (wm * 128 + fr) * BK;
  const int bBase = (wn * 64 + fr) * BK;

  floatx4 acc[8][4] = {};
  bf16x8 af[8][2], bfv[4][2];

#define GLL(src, dst)                                                  \
  __builtin_amdgcn_global_load_lds(                                    \
      (const __attribute__((address_space(1))) void*)(src),            \
      (__attribute__((address_space(3))) void*)(dst), 16, 0, 0)

  // stage one half-tile (mat 0=A 1=B, h = row-half) of K-tile kt into buf c
#define STAGE_H(c, mat, h, kt)                                         \
  do {                                                                 \
    const unsigned short* _g = (mat) ? gB : gA;                        \
    GLL(_g + (size_t)((h) * 128) * Hdim + (size_t)(kt) * BK,           \
        &lds[c][mat][((h) * 128 + wave * 8) * BK]);                    \
    GLL(_g + (size_t)((h) * 128 + 64) * Hdim + (size_t)(kt) * BK,      \
        &lds[c][mat][((h) * 128 + 64 + wave * 8) * BK]);               \
  } while (0)

#define READ_A(c, lo)                                                  \
  do {                                                                 \
    _Pragma("unroll") for (int mi = (lo); mi < (lo) + 4; ++mi) {       \
      af[mi][0] = *(const bf16x8*)&lds[c][0][aBase + mi * 16 * BK + kx0]; \
      af[mi][1] = *(const bf16x8*)&lds[c][0][aBase + mi * 16 * BK + kx1]; \
    }                                                                  \
  } while (0)

#define READ_B(c, lo)                                                  \
  do {                                                                 \
    _Pragma("unroll") for (int ni = (lo); ni < (lo) + 2; ++ni) {       \
      bfv[ni][0] = *(const bf16x8*)&lds[c][1][bBase + ni * 16 * BK + kx0]; \
      bfv[ni][1] = *(const bf16x8*)&lds[c][1][bBase + ni * 16 * BK + kx1]; \
    }                                                                  \
  } while (0)

#define MFMA_Q(M0, N0)                                                 \
  do {                                                                 \
    __builtin_amdgcn_s_setprio(1);                                     \
    _Pragma("unroll") for (int mi = (M0); mi < (M0) + 4; ++mi)         \
      _Pragma("unroll") for (int ni = (N0); ni < (N0) + 2; ++ni) {     \
        acc[mi][ni] = __builtin_amdgcn_mfma_f32_16x16x32_bf16(         \
            af[mi][0], bfv[ni][0], acc[mi][ni], 0, 0, 0);              \
        acc[mi][ni] = __builtin_amdgcn_mfma_f32_16x16x32_bf16(         \
            af[mi][1], bfv[ni][1], acc[mi][ni], 0, 0, 0);              \
      }                                                                \
    __builtin_amdgcn_s_setprio(0);                                     \
  } while (0)

#define BAR __builtin_amdgcn_s_barrier()
#define LGKM0 asm volatile("s_waitcnt lgkmcnt(0)" ::: "memory")
#define GATE4 asm volatile("s_waitcnt vmcnt(4)\n\ts_barrier" ::: "memory")
#define GATE0 asm volatile("s_waitcnt vmcnt(0)\n\ts_barrier" ::: "memory")

  // DO_B: stage B(kt+1)->o at P0/P1.  DO_A: stage A(kt+2)->c at P2/P3.
#define TILE_BODY(c, o, kt, DO_B, DO_A, GATE)                          \
  do {                                                                 \
    /* P0 */                                                           \
    if (DO_B) STAGE_H(o, 1, 0, (kt) + 1);                              \
    READ_A(c, 0);                                                      \
    READ_B(c, 0);                                                      \
    BAR; LGKM0;                                                        \
    MFMA_Q(0, 0);                                                      \
    /* P1 */                                                           \
    if (DO_B) STAGE_H(o, 1, 1, (kt) + 1);                              \
    READ_A(c, 4);                                                      \
    BAR; LGKM0;                                                        \
    MFMA_Q(4, 0);                                                      \
    BAR;  /* collective: all af reads of buf c complete -> c.A free */ \
    /* P2 */                                                           \
    if (DO_A) STAGE_H(c, 0, 0, (kt) + 2);                              \
    READ_B(c, 2);                                                      \
    BAR; LGKM0;                                                        \
    MFMA_Q(0, 2);                                                      \
    BAR;  /* collective: all reads of buf c complete */                \
    /* P3 */                                                           \
    if (DO_A) STAGE_H(c, 0, 1, (kt) + 2);                              \
    GATE;                                                              \
    MFMA_Q(4, 2);                                                      \
  } while (0)

  // prologue: tile 0 fully + tile 1 A halves (12 GLLs), gate to 4
  STAGE_H(0, 0, 0, 0);
  STAGE_H(0, 0, 1, 0);
  STAGE_H(0, 1, 0, 0);
  STAGE_H(0, 1, 1, 0);
  STAGE_H(1, 0, 0, 1);
  STAGE_H(1, 0, 1, 1);
  GATE4;

#pragma unroll 1
  for (int t = 0; t < NT - 2; t += 2) {
    TILE_BODY(0, 1, t, 1, 1, GATE4);
    TILE_BODY(1, 0, t + 1, 1, 1, GATE4);
  }
  // tile NT-2 (buf 0): stages B(NT-1)->buf1; no A stage; GATE0 drains
  // A(15)+B(15) (B(15) issued 2 phases earlier).
  TILE_BODY(0, 1, NT - 2, 1, 0, GATE0);
  // tile NT-1 (buf 1): all data resident & retired; no stages, no gate.
  TILE_BODY(1, 0, NT - 1, 0, 0, (void)0);

#undef GLL
#undef STAGE_H
#undef READ_A
#undef READ_B
#undef MFMA_Q
#undef BAR
#undef LGKM0
#undef GATE4
#undef GATE0
#undef TILE_BODY

  // epilogue: C/D layout col=lane&15, row=(lane>>4)*4+reg  [m89-verified]
  const int col0 = n_blk + wn * 64 + fr;
  const int row0 = m_blk + wm * 128 + fq * 4;
#pragma unroll
  for (int ni = 0; ni < 4; ++ni) {
    const float bs = bias[col0 + ni * 16];
#pragma unroll
    for (int mi = 0; mi < 8; ++mi) {
      float* cp = C + (size_t)(row0 + mi * 16) * Ldim + (col0 + ni * 16);
      floatx4 v = acc[mi][ni];
      cp[0 * (size_t)Ldim] = v.x + bs;
      cp[1 * (size_t)Ldim] = v.y + bs;
      cp[2 * (size_t)Ldim] = v.z + bs;
      cp[3 * (size_t)Ldim] = v.w + bs;
    }
  }
}

extern "C" void kernel_launch(void* const* d_in, const int* in_sizes, int n_in,
                              void* d_out, int out_size, void* d_ws, size_t ws_size,
                              hipStream_t stream) {
  const float* X = (const float*)d_in[0];  // bert_output [B,H]
  const float* E = (const float*)d_in[1];  // label_embed [L,H]
  const float* W = (const float*)d_in[2];  // W [L,H]
  const float* b = (const float*)d_in[3];  // b [L]
  // d_in[4] = labels, unused by the reference output.
  float* out = (float*)d_out;

  unsigned short* Xb = (unsigned short*)d_ws;                 // 8 MB
  unsigned short* Wb = Xb + (size_t)Bdim * Hdim;              // 8 MB
  float* bias = (float*)(Wb + (size_t)Ldim * Hdim);           // 16 KB

  prep_kernel<<<2048, 256, 0, stream>>>(X, E, W, b, Xb, Wb, bias);
  dim3 grid(Ldim / BN, Bdim / BM);
  gemm_bias_kernel<<<grid, 512, 0, stream>>>(Xb, Wb, bias, out);
}